// Round 7
// baseline (530.365 us; speedup 1.0000x reference)
//
#include <hip/hip_runtime.h>
#include <math.h>

// Problem constants (from reference setup_inputs)
constexpr int  Bn  = 8;        // batch
constexpr int  Cin = 512;      // input channels
constexpr int  Nn  = 4096;     // H*W
constexpr int  Ck  = 256;      // key/query channels
constexpr int  Cv  = 256;      // value channels
constexpr int  Co  = 512;      // output channels

// d_out layout: [out | feat | feat | value]
constexpr size_t F1_OFF  = (size_t)Bn * Co * Nn;
constexpr size_t F2_OFF  = F1_OFF + (size_t)Bn * Ck * Nn;
constexpr size_t VAL_OFF = F2_OFF + (size_t)Bn * Ck * Nn;

typedef __attribute__((ext_vector_type(8)))  short  short8;   // 8 x bf16 frag
typedef __attribute__((ext_vector_type(16))) float  f32x16;   // 32x32 C/D frag
typedef __attribute__((ext_vector_type(8)))  ushort ushort8;

static __device__ __forceinline__ ushort f2bf(float f) {
    union { float f; unsigned u; } x; x.f = f;
    unsigned r = x.u + 0x7fffu + ((x.u >> 16) & 1u);   // RNE (no NaN inputs here)
    return (ushort)(r >> 16);
}

static __device__ __forceinline__ void gll16(const void* g, void* l) {
    __builtin_amdgcn_global_load_lds(
        (const __attribute__((address_space(1))) void*)g,
        (__attribute__((address_space(3))) void*)l, 16, 0, 0);
}

// ---------------------------------------------------------------------------
// Cast the three weight matrices to bf16 (131072 elements each) and zero the
// BN-stat accumulators (ss[0..511]) for this launch.
// ---------------------------------------------------------------------------
__global__ __launch_bounds__(256) void cast_w(const float* __restrict__ a,
                                              const float* __restrict__ b,
                                              const float* __restrict__ c,
                                              ushort* __restrict__ da,
                                              ushort* __restrict__ db,
                                              ushort* __restrict__ dc,
                                              float* __restrict__ ss)
{
    const int tid   = blockIdx.x * 256 + threadIdx.x;
    if (tid < 512) ss[tid] = 0.f;                // zero stat accumulators
    const int which = tid >> 14;                 // 16384 threads per matrix
    const int off   = (tid & 16383) * 8;
    const float* s = (which == 0) ? a : (which == 1) ? b : c;
    ushort*      d = (which == 0) ? da : (which == 1) ? db : dc;
    const float4 u = *(const float4*)(s + off);
    const float4 v = *(const float4*)(s + off + 4);
    ushort8 o;
    o[0] = f2bf(u.x); o[1] = f2bf(u.y); o[2] = f2bf(u.z); o[3] = f2bf(u.w);
    o[4] = f2bf(v.x); o[5] = f2bf(v.y); o[6] = f2bf(v.z); o[7] = f2bf(v.w);
    *(ushort8*)(d + off) = o;
}

// ---------------------------------------------------------------------------
// src fp32 [B][C][Nn] -> dst bf16 [B][Nn][C]  (LDS transpose, 64x64 tile)
// float4 reads (16B/lane), ushort8 writes (16B/lane).
// ---------------------------------------------------------------------------
__global__ __launch_bounds__(256) void transpose_c(const float* __restrict__ src,
                                                   ushort* __restrict__ dst, int C)
{
    const int b  = blockIdx.z;
    const int c0 = blockIdx.y * 64;
    const int n0 = blockIdx.x * 64;
    const int t  = threadIdx.x;
    __shared__ float T[64][65];
#pragma unroll
    for (int p = 0; p < 4; ++p) {                 // 1024 float4 loads
        const int flat = p * 256 + t;
        const int cc = flat >> 4, nn4 = (flat & 15) * 4;
        const float4 v = *(const float4*)(
            src + ((size_t)b * C + c0 + cc) * Nn + n0 + nn4);
        T[cc][nn4]     = v.x; T[cc][nn4 + 1] = v.y;
        T[cc][nn4 + 2] = v.z; T[cc][nn4 + 3] = v.w;
    }
    __syncthreads();
#pragma unroll
    for (int p = 0; p < 2; ++p) {                 // 512 ushort8 stores
        const int flat = p * 256 + t;
        const int nn = flat >> 3, cc0 = (flat & 7) * 8;
        ushort8 o;
#pragma unroll
        for (int i = 0; i < 8; ++i) o[i] = f2bf(T[cc0 + i][nn]);
        *(ushort8*)(dst + ((size_t)b * Nn + n0 + nn) * C + c0 + cc0) = o;
    }
}

// ---------------------------------------------------------------------------
// Fused QK/V GEMM + BN partial stats:
//   qk[b][m][n]  = sum_k Wk[m][k] * XT[b][n][k] + bk[m]        (fp32)
//   val[b][m][n] = sum_k Wv[m][k] * XT[b][n][k] + bv[m]        (fp32 + bf16)
//   ss[o]    += sum_n qk[b][o][n-tile]      (shuffle-reduced + atomicAdd)
//   ss[Ck+o] += sum_n qk^2
// Replaces the separate bn_stats kernel (one fewer 33.5 MB pass + launch).
// ---------------------------------------------------------------------------
__global__ __launch_bounds__(256) void gemm_qv(const ushort* __restrict__ XT,
                                               const ushort* __restrict__ Wkb,
                                               const ushort* __restrict__ Wvb,
                                               const float*  __restrict__ bk,
                                               const float*  __restrict__ bv,
                                               float* __restrict__ qk,
                                               float* __restrict__ val,
                                               ushort* __restrict__ valB,
                                               float* __restrict__ ss)
{
    const int b  = blockIdx.z;
    const int m0 = blockIdx.y * 128;
    const int n0 = blockIdx.x * 128;
    const int t  = threadIdx.x;
    const int w  = t >> 6, L = t & 63;
    const int l31 = L & 31, hl = L >> 5;
    const int wm = (w >> 1) * 64, wn = (w & 1) * 64;

    __shared__ __align__(16) short AsK[128][72];
    __shared__ __align__(16) short AsV[128][72];
    __shared__ __align__(16) short Bs[128][72];

    const ushort* Xb = XT + (size_t)b * Nn * Cin;

    f32x16 accK[2][2], accV[2][2];
#pragma unroll
    for (int a = 0; a < 2; ++a)
#pragma unroll
        for (int bb = 0; bb < 2; ++bb)
#pragma unroll
            for (int r = 0; r < 16; ++r) { accK[a][bb][r] = 0.f; accV[a][bb][r] = 0.f; }

    for (int k0 = 0; k0 < Cin; k0 += 64) {
        __syncthreads();
#pragma unroll
        for (int p = 0; p < 4; ++p) {            // stage Wk, Wv, xT tiles
            const int e   = p * 256 + t;
            const int row = e >> 3, ko = (e & 7) * 8;
            *(short8*)&AsK[row][ko] =
                *(const short8*)(Wkb + (size_t)(m0 + row) * Cin + k0 + ko);
            *(short8*)&AsV[row][ko] =
                *(const short8*)(Wvb + (size_t)(m0 + row) * Cin + k0 + ko);
            *(short8*)&Bs[row][ko] =
                *(const short8*)(Xb + (size_t)(n0 + row) * Cin + k0 + ko);
        }
        __syncthreads();
#pragma unroll
        for (int kc = 0; kc < 4; ++kc) {
            short8 Ak[2], Av[2], Bf[2];
#pragma unroll
            for (int a = 0; a < 2; ++a) {
                Ak[a] = *(const short8*)&AsK[wm + a * 32 + l31][kc * 16 + hl * 8];
                Av[a] = *(const short8*)&AsV[wm + a * 32 + l31][kc * 16 + hl * 8];
            }
#pragma unroll
            for (int bb = 0; bb < 2; ++bb)
                Bf[bb] = *(const short8*)&Bs[wn + bb * 32 + l31][kc * 16 + hl * 8];
#pragma unroll
            for (int a = 0; a < 2; ++a)
#pragma unroll
                for (int bb = 0; bb < 2; ++bb) {
                    accK[a][bb] = __builtin_amdgcn_mfma_f32_32x32x16_bf16(
                        Ak[a], Bf[bb], accK[a][bb], 0, 0, 0);
                    accV[a][bb] = __builtin_amdgcn_mfma_f32_32x32x16_bf16(
                        Av[a], Bf[bb], accV[a][bb], 0, 0, 0);
                }
        }
    }

    // epilogue: D row=(r&3)+8*(r>>2)+4*hl, col=l31 ; + channel stat partials
#pragma unroll
    for (int a = 0; a < 2; ++a)
#pragma unroll
        for (int r = 0; r < 16; ++r) {
            const int row = (r & 3) + 8 * (r >> 2) + 4 * hl;
            const int o   = m0 + wm + a * 32 + row;
            const float bkv = bk[o], bvv = bv[o];
            const size_t base = ((size_t)b * Ck + o) * Nn + n0 + wn + l31;
            const float q0 = accK[a][0][r] + bkv;
            const float q1 = accK[a][1][r] + bkv;
            qk[base]      = q0;
            qk[base + 32] = q1;
            const float v0 = accV[a][0][r] + bvv;
            const float v1 = accV[a][1][r] + bvv;
            val[base]       = v0;
            val[base + 32]  = v1;
            valB[base]      = f2bf(v0);
            valB[base + 32] = f2bf(v1);
            // per-channel partial: sum + sumsq over this block's 2 n-values,
            // reduced across the 32-lane group (same channel o within group)
            float sp = q0 + q1;
            float qp = q0 * q0 + q1 * q1;
#pragma unroll
            for (int m = 1; m <= 16; m <<= 1) {
                sp += __shfl_xor(sp, m, 64);
                qp += __shfl_xor(qp, m, 64);
            }
            if (l31 == 0) {
                atomicAdd(&ss[o], sp);
                atomicAdd(&ss[Ck + o], qp);
            }
        }
}

// ---------------------------------------------------------------------------
// Fused BN-apply + ReLU + channel transpose. Computes scale/shift inline from
// the accumulated sums (ss[o]=Σ, ss[Ck+o]=Σx²); writes f1/f2 fp32 (coalesced)
// AND featT bf16 [B][Nn][Ck] via LDS transpose.
// ---------------------------------------------------------------------------
__global__ __launch_bounds__(256) void bn_relu_t(const float* __restrict__ qk,
                                                 const float* __restrict__ ssv,
                                                 const float* __restrict__ gamma,
                                                 const float* __restrict__ beta,
                                                 float* __restrict__ f1,
                                                 float* __restrict__ f2,
                                                 ushort* __restrict__ featT)
{
    const int b  = blockIdx.z;
    const int c0 = blockIdx.y * 64;
    const int n0 = blockIdx.x * 64;
    const int t  = threadIdx.x;
    constexpr float RCNT = 1.f / (float)(Bn * Nn);
    __shared__ float T[64][65];
#pragma unroll
    for (int p = 0; p < 4; ++p) {                 // float4 load + BN + relu
        const int flat = p * 256 + t;
        const int cc = flat >> 4, nn4 = (flat & 15) * 4;
        const int c = c0 + cc;
        const size_t gidx = ((size_t)b * Ck + c) * Nn + n0 + nn4;
        const float mean = ssv[c] * RCNT;
        const float var  = ssv[Ck + c] * RCNT - mean * mean;
        const float inv  = rsqrtf(var + 1e-5f);
        const float sc   = gamma[c] * inv;
        const float sh   = beta[c] - mean * sc;
        const float4 v = *(const float4*)(qk + gidx);
        float4 r;
        r.x = fmaxf(v.x * sc + sh, 0.f);
        r.y = fmaxf(v.y * sc + sh, 0.f);
        r.z = fmaxf(v.z * sc + sh, 0.f);
        r.w = fmaxf(v.w * sc + sh, 0.f);
        *(float4*)(f1 + gidx) = r;
        *(float4*)(f2 + gidx) = r;
        T[cc][nn4]     = r.x; T[cc][nn4 + 1] = r.y;
        T[cc][nn4 + 2] = r.z; T[cc][nn4 + 3] = r.w;
    }
    __syncthreads();
#pragma unroll
    for (int p = 0; p < 2; ++p) {                 // transposed ushort8 stores
        const int flat = p * 256 + t;
        const int nn = flat >> 3, cc0 = (flat & 7) * 8;
        ushort8 o;
#pragma unroll
        for (int i = 0; i < 8; ++i) o[i] = f2bf(T[cc0 + i][nn]);
        *(ushort8*)(featT + ((size_t)b * Nn + n0 + nn) * Ck + c0 + cc0) = o;
    }
}

// ---------------------------------------------------------------------------
// bf16 MFMA flash attention, no-max softmax (scores >= 0, <= ~33).
//   featT [B][Nn][Ck] bf16, valB [B][Cv][Nn] bf16, ctx OUT bf16 [B][Nn][Cv]
//
// Round-7: PV i2cv4 split — LDS reads at the 1:1 read:MFMA floor.
//   PV wave (iq = w>>2, cq = w&3) owns 64 i rows x 64 cv, full 64 j:
//   each P read serves 2 cv-blocks, each V read serves 2 i-blocks ->
//   P 8 + V 8 = 16 reads for 16 MFMA (was 4 + 16 = 20). Per CU-tile LDS
//   reads 304 -> 272. Oacc[4] = (iA,cvB) blocks, same 64 regs, no spill.
// QK unchanged (ig = w>>1, ch = w&1): K 16 reads (floor — Q-register limit
// pins i-rows/wave at 32). Kept: swapped QK^T, cvt_pk, permlane pack,
// gll16 + per-row rotation, 1 barrier/tile, batch->XCD grid, setprio.
// LDS: K 2x32K + V 2x32K + P 2x16K = 163840 B.
// ---------------------------------------------------------------------------
constexpr int LDS_BYTES = 163840;

__global__ __launch_bounds__(512) void attn_mfma(const ushort* __restrict__ featT,
                                                 const ushort* __restrict__ valB,
                                                 ushort* __restrict__ ctx)
{
    extern __shared__ __align__(16) char lds[];
    char* ldsK = lds;              // [buf][64 rows][512 B]  (rotated image)
    char* ldsV = lds + 65536;      // [buf][256 rows][128 B] (rotated image)
    char* ldsP = lds + 131072;     // [buf][IG 4][jb 4][hl 2][32 lanes x 16 B]

    const int b   = blockIdx.x;                  // batch -> XCD affinity
    const int i0  = blockIdx.y * 128;
    const int t   = threadIdx.x;
    const int w   = t >> 6;
    const int L   = t & 63;
    const int l31 = L & 31, hl = L >> 5;
    const int ig  = w >> 1;                      // QK: i-group 0..3 (32 rows)
    const int ch  = w & 1;                       // QK: j-half owner
    const int iq  = w >> 2;                      // PV: i-half 0..1 (64 rows)
    const int cq  = w & 3;                       // PV: cv-quarter 0..3 (64 cv)
    const int jsel = ch * 32;

    // read-side rotation bases (verified rounds 3-6)
    const int rbK  = hl * 16 + (((jsel + l31) << 4) & 511);
    const int rotV = (l31 << 4) & 127;

    const ushort* F = featT + (size_t)b * Nn * Ck;
    const ushort* V = valB  + (size_t)b * Cv * Nn;
    const char*   Vg = (const char*)V;

    constexpr float CEXP = 0.09016844005556021f;  // log2(e)/16
    constexpr int NT = Nn / 64;                   // 64 j-tiles

#define STAGE_K(J0, BUF) do {                                                  \
        const char* Kg_ = (const char*)(F + (size_t)(J0) * Ck);                \
        char* Kd_ = ldsK + (BUF) * 32768;                                      \
        _Pragma("unroll")                                                      \
        for (int p_ = 0; p_ < 4; ++p_) {                                       \
            const int c_ = w * 4 + p_;                                         \
            const int o_ = c_ * 1024 + L * 16;                                 \
            const int rK_ = o_ >> 9;                                           \
            gll16(Kg_ + rK_ * 512 + ((o_ - rK_ * 16) & 511), Kd_ + c_ * 1024); \
        }                                                                      \
    } while (0)

#define STAGE_V(J0, BUF) do {                                                  \
        char* Vd_ = ldsV + (BUF) * 32768;                                      \
        _Pragma("unroll")                                                      \
        for (int p_ = 0; p_ < 4; ++p_) {                                       \
            const int c_ = w * 4 + p_;                                         \
            const int o_ = c_ * 1024 + L * 16;                                 \
            const int rV_ = o_ >> 7;                                           \
            gll16(Vg + (size_t)rV_ * (Nn * 2) + (size_t)(J0) * 2               \
                     + ((o_ - rV_ * 16) & 127), Vd_ + c_ * 1024);              \
        }                                                                      \
    } while (0)

    // prologue: K(0) staged; Q fragments; drain + align all waves
    STAGE_K(0, 0);
    short8 Qf[16];
    {
        const ushort* qp = F + ((size_t)(i0 + ig * 32 + l31)) * Ck + hl * 8;
#pragma unroll
        for (int kc = 0; kc < 16; ++kc)
            Qf[kc] = *(const short8*)(qp + kc * 16);
    }
    asm volatile("s_waitcnt vmcnt(0)" ::: "memory");
    __builtin_amdgcn_s_barrier();

    f32x16 Oacc[4];                               // [iA*2 + cvB]
#pragma unroll
    for (int c = 0; c < 4; ++c)
#pragma unroll
        for (int r = 0; r < 16; ++r) Oacc[c][r] = 0.f;
    float lsum = 0.f;

    int cur = 0;
    for (int s = 0; s < NT; ++s) {
        // stage K(s+1) and V(s) — consumed next iteration
        const int jn = (s + 1 < NT ? s + 1 : NT - 1) * 64;
        STAGE_K(jn, cur ^ 1);
        STAGE_V((size_t)s * 64, cur);

        // ---- QK(s): S^T[j][i] from K[cur] ----
        const char* Kr = ldsK + cur * 32768 + (jsel + l31) * 512;
        f32x16 Sa, Sb;
#pragma unroll
        for (int r = 0; r < 16; ++r) { Sa[r] = 0.f; Sb[r] = 0.f; }
        __builtin_amdgcn_s_setprio(1);
#pragma unroll
        for (int kc = 0; kc < 8; ++kc) {
            const short8 K0 = *(const short8*)(Kr + ((kc * 64      + rbK) & 511));
            const short8 K1 = *(const short8*)(Kr + ((kc * 64 + 32 + rbK) & 511));
            Sa = __builtin_amdgcn_mfma_f32_32x32x16_bf16(K0, Qf[2 * kc],     Sa, 0, 0, 0);
            Sb = __builtin_amdgcn_mfma_f32_32x32x16_bf16(K1, Qf[2 * kc + 1], Sb, 0, 0, 0);
        }
        __builtin_amdgcn_s_setprio(0);

        // ---- PV(s-1): i2cv4 — 64 i x 64 cv, full j, from buf cur^1 ----
        if (s > 0) {
            const char* Vb2 = ldsV + (cur ^ 1) * 32768 + (cq * 64 + l31) * 128;
            const char* Pb  = ldsP + (cur ^ 1) * 16384 + hl * 512 + l31 * 16;
            __builtin_amdgcn_s_setprio(1);
#pragma unroll
            for (int jb = 0; jb < 4; ++jb) {
                short8 Pa[2];
#pragma unroll
                for (int iA = 0; iA < 2; ++iA)
                    Pa[iA] = *(const short8*)(Pb + ((iq * 2 + iA) * 4 + jb) * 1024);
                const int jbyte = jb * 32 + hl * 16;
#pragma unroll
                for (int cvB = 0; cvB < 2; ++cvB) {
                    const short8 Vf = *(const short8*)(Vb2 + cvB * 4096
                                         + ((jbyte + rotV) & 127));
#pragma unroll
                    for (int iA = 0; iA < 2; ++iA)
                        Oacc[iA * 2 + cvB] = __builtin_amdgcn_mfma_f32_32x32x16_bf16(
                            Pa[iA], Vf, Oacc[iA * 2 + cvB], 0, 0, 0);
                }
            }
            __builtin_amdgcn_s_setprio(0);
        }

        // ---- softmax: exp + cvt_pk (hw RNE) + unrounded lsum ----
        unsigned pw[8];
#pragma unroll
        for (int r2 = 0; r2 < 8; ++r2) {
            const float p0 = exp2f((Sa[2 * r2]     + Sb[2 * r2])     * CEXP);
            const float p1 = exp2f((Sa[2 * r2 + 1] + Sb[2 * r2 + 1]) * CEXP);
            lsum += p0 + p1;
            unsigned pk;
            asm("v_cvt_pk_bf16_f32 %0, %1, %2" : "=v"(pk) : "v"(p0), "v"(p1));
            pw[r2] = pk;
        }
        {
            char* Pw = ldsP + cur * 16384
                       + ((ig * 4 + ch * 2) * 2 + hl) * 512 + l31 * 16;
#pragma unroll
            for (int g = 0; g < 2; ++g) {
                auto s02 = __builtin_amdgcn_permlane32_swap(pw[4 * g + 0], pw[4 * g + 2],
                                                            false, false);
                auto s13 = __builtin_amdgcn_permlane32_swap(pw[4 * g + 1], pw[4 * g + 3],
                                                            false, false);
                union { unsigned u[4]; short8 s; } pu;
                pu.u[0] = s02[0]; pu.u[1] = s13[0]; pu.u[2] = s02[1]; pu.u[3] = s13[1];
                *(short8*)(Pw + g * 1024) = pu.s;
            }
        }

        // drain MY glls + ds ops, then align: everyone's staging visible
        asm volatile("s_waitcnt vmcnt(0) lgkmcnt(0)" ::: "memory");
        __builtin_amdgcn_s_barrier();
        cur ^= 1;
    }
#undef STAGE_K
#undef STAGE_V

    // ---- epilogue PV(NT-1): same i2cv4 pattern from buf cur^1 ----
    {
        const char* Vb2 = ldsV + (cur ^ 1) * 32768 + (cq * 64 + l31) * 128;
        const char* Pb  = ldsP + (cur ^ 1) * 16384 + hl * 512 + l31 * 16;
#pragma unroll
        for (int jb = 0; jb < 4; ++jb) {
            short8 Pa[2];
#pragma unroll
            for (int iA = 0; iA < 2; ++iA)
                Pa[iA] = *(const short8*)(Pb + ((iq * 2 + iA) * 4 + jb) * 1024);
            const int jbyte = jb * 32 + hl * 16;
#pragma unroll
            for (int cvB = 0; cvB < 2; ++cvB) {
                const short8 Vf = *(const short8*)(Vb2 + cvB * 4096
                                     + ((jbyte + rotV) & 127));
#pragma unroll
                for (int iA = 0; iA < 2; ++iA)
                    Oacc[iA * 2 + cvB] = __builtin_amdgcn_mfma_f32_32x32x16_bf16(
                        Pa[iA], Vf, Oacc[iA * 2 + cvB], 0, 0, 0);
            }
        }
    }

    // ---- l merge (hl in-reg, ch via LDS; Lr aliases dead P buf 0) ----
    {
        unsigned a = __float_as_uint(lsum), bcopy = a;
        auto sw = __builtin_amdgcn_permlane32_swap(a, bcopy, false, false);
        lsum = __uint_as_float(sw[0]) + __uint_as_float(sw[1]);
    }
    float* Lr = (float*)ldsP;          // P buf0 dead (epilogue reads buf1)
    Lr[(ig * 2 + ch) * 32 + l31] = lsum;
    asm volatile("s_waitcnt lgkmcnt(0)" ::: "memory");
    __builtin_amdgcn_s_barrier();

    // store: wave owns rows i0 + iq*64 + iA*32 + row, cols cq*64 + cvB*32 + l31
    ushort* Cb = ctx + ((size_t)b * Nn + i0 + iq * 64) * Cv + cq * 64;
#pragma unroll
    for (int iA = 0; iA < 2; ++iA) {
        const int IG = iq * 2 + iA;
#pragma unroll
        for (int r = 0; r < 16; ++r) {
            const int row = (r & 3) + 8 * (r >> 2) + 4 * hl;
            const float lt = Lr[(IG * 2) * 32 + row] + Lr[(IG * 2 + 1) * 32 + row];
            const float linv = 1.f / lt;
            ushort* cp = Cb + (size_t)(iA * 32 + row) * Cv + l31;
#pragma unroll
            for (int cvB = 0; cvB < 2; ++cvB)
                cp[cvB * 32] = f2bf(Oacc[iA * 2 + cvB][r] * linv);
        }
    }
}

// ---------------------------------------------------------------------------
// Final 1x1 conv GEMM (unchanged structure):
//   out[b][m][n] = sum_k Wb[m][k] * XT[b][n][k] + bias[m]
// ---------------------------------------------------------------------------
template <int K>
__global__ __launch_bounds__(256) void gemm_bf(const ushort* __restrict__ XT,
                                               const ushort* __restrict__ Wb,
                                               const float*  __restrict__ bias,
                                               float* __restrict__ out,
                                               int M)
{
    const int b  = blockIdx.z;
    const int m0 = blockIdx.y * 128;
    const int n0 = blockIdx.x * 128;
    const int t  = threadIdx.x;
    const int w  = t >> 6, L = t & 63;
    const int l31 = L & 31, hl = L >> 5;
    const int wm = (w >> 1) * 64, wn = (w & 1) * 64;

    __shared__ __align__(16) short As[128][72];   // [m][k]
    __shared__ __align__(16) short Bs[128][72];   // [n][k]

    const ushort* Xb = XT + (size_t)b * Nn * K;

    f32x16 acc[2][2];
#pragma unroll
    for (int a = 0; a < 2; ++a)
#pragma unroll
        for (int bb = 0; bb < 2; ++bb)
#pragma unroll
            for (int r = 0; r < 16; ++r) acc[a][bb][r] = 0.f;

    for (int k0 = 0; k0 < K; k0 += 64) {
        __syncthreads();
#pragma unroll
        for (int p = 0; p < 4; ++p) {            // stage 128x64 A and B tiles
            const int e   = p * 256 + t;
            const int row = e >> 3, ko = (e & 7) * 8;
            *(short8*)&As[row][ko] =
                *(const short8*)(Wb + (size_t)(m0 + row) * K + k0 + ko);
            *(short8*)&Bs[row][ko] =
                *(const short8*)(Xb + (size_t)(n0 + row) * K + k0 + ko);
        }
        __syncthreads();
#pragma unroll
        for (int kc = 0; kc < 4; ++kc) {
            short8 Af[2], Bf[2];
#pragma unroll
            for (int a = 0; a < 2; ++a)
                Af[a] = *(const short8*)&As[wm + a * 32 + l31][kc * 16 + hl * 8];
#pragma unroll
            for (int bb = 0; bb < 2; ++bb)
                Bf[bb] = *(const short8*)&Bs[wn + bb * 32 + l31][kc * 16 + hl * 8];
#pragma unroll
            for (int a = 0; a < 2; ++a)
#pragma unroll
                for (int bb = 0; bb < 2; ++bb)
                    acc[a][bb] = __builtin_amdgcn_mfma_f32_32x32x16_bf16(
                        Af[a], Bf[bb], acc[a][bb], 0, 0, 0);
        }
    }

    // epilogue: D row=(r&3)+8*(r>>2)+4*hl, col=l31
#pragma unroll
    for (int a = 0; a < 2; ++a)
#pragma unroll
        for (int r = 0; r < 16; ++r) {
            const int row = (r & 3) + 8 * (r >> 2) + 4 * hl;
            const int o   = m0 + wm + a * 32 + row;
            const float bv = bias[o];
            const size_t base = ((size_t)b * M + o) * Nn + n0 + wn + l31;
#pragma unroll
            for (int bb = 0; bb < 2; ++bb)
                out[base + bb * 32] = acc[a][bb][r] + bv;
        }
}

// ---------------------------------------------------------------------------
extern "C" void kernel_launch(void* const* d_in, const int* in_sizes, int n_in,
                              void* d_out, int out_size, void* d_ws, size_t ws_size,
                              hipStream_t stream)
{
    const float* x     = (const float*)d_in[0];
    const float* Wk    = (const float*)d_in[1];
    const float* bk    = (const float*)d_in[2];
    const float* gamma = (const float*)d_in[3];
    const float* beta  = (const float*)d_in[4];
    const float* Wv    = (const float*)d_in[5];
    const float* bv    = (const float*)d_in[6];
    const float* Ww    = (const float*)d_in[7];
    const float* bw    = (const float*)d_in[8];

    float* out = (float*)d_out;
    float* f1  = out + F1_OFF;
    float* f2  = out + F2_OFF;
    float* val = out + VAL_OFF;

    // workspace packing (51.1 MB), with aliasing over dead xT:
    //   xT    : [0 .. 16,777,216) ushorts   live steps 2-3
    //   featT : alias xT[0 .. 8,388,608)    live steps 4-5
    //   ctxb  : alias xT[8,388,608 .. )     live steps 5-6
    ushort* xT    = (ushort*)d_ws;                       // [B][Nn][Cin]
    ushort* featT = xT;                                  // [B][Nn][Ck]
    ushort* ctxb  = xT + (size_t)8388608;                // [B][Nn][Cv]
    ushort* valB  = xT + (size_t)16777216;               // [B][Cv][Nn]
    ushort* Wkb   = valB + (size_t)8388608;
    ushort* Wvb   = Wkb + 131072;
    ushort* Wwb   = Wvb + 131072;
    float*  ss    = (float*)(Wwb + 131072);              // 512 floats (Σ, Σx²)

    // one-time: allow 160 KB dynamic LDS for the attention kernel
    static bool attn_attr_set = false;
    if (!attn_attr_set) {
        (void)hipFuncSetAttribute((const void*)attn_mfma,
                                  hipFuncAttributeMaxDynamicSharedMemorySize,
                                  LDS_BYTES);
        attn_attr_set = true;
    }

    // 1) weights -> bf16 ; zero BN-stat accumulators
    cast_w<<<192, 256, 0, stream>>>(Wk, Wv, Ww, Wkb, Wvb, Wwb, ss);
    // 2) x -> xT bf16 [B][Nn][Cin]
    transpose_c<<<dim3(Nn / 64, Cin / 64, Bn), 256, 0, stream>>>(x, xT, Cin);
    // 3) fused: qk = Wk*x + bk, value = Wv*x + bv, BN channel sums -> ss
    gemm_qv<<<dim3(Nn / 128, Ck / 128, Bn), 256, 0, stream>>>(
        xT, Wkb, Wvb, bk, bv, f1, val, valB, ss);
    // 4) fused: feat = relu(norm(qk)) -> f1, f2 AND featT bf16 (xT dead)
    bn_relu_t<<<dim3(Nn / 64, Ck / 64, Bn), 256, 0, stream>>>(
        f1, ss, gamma, beta, f1, f2, featT);
    // 5) flash attention -> ctx bf16 [B][Nn][Cv]
    attn_mfma<<<dim3(Bn, Nn / 128), 512, LDS_BYTES, stream>>>(featT, valB, ctxb);
    // 6) out = Ww*ctx + bw
    gemm_bf<256><<<dim3(Nn / 128, Co / 128, Bn), 256, 0, stream>>>(
        ctxb, Wwb, bw, out, Co);
}

// Round 8
// 459.214 us; speedup vs baseline: 1.1549x; 1.1549x over previous
//
#include <hip/hip_runtime.h>
#include <math.h>

// Problem constants (from reference setup_inputs)
constexpr int  Bn  = 8;        // batch
constexpr int  Cin = 512;      // input channels
constexpr int  Nn  = 4096;     // H*W
constexpr int  Ck  = 256;      // key/query channels
constexpr int  Cv  = 256;      // value channels
constexpr int  Co  = 512;      // output channels

// d_out layout: [out | feat | feat | value]
constexpr size_t F1_OFF  = (size_t)Bn * Co * Nn;
constexpr size_t F2_OFF  = F1_OFF + (size_t)Bn * Ck * Nn;
constexpr size_t VAL_OFF = F2_OFF + (size_t)Bn * Ck * Nn;

typedef __attribute__((ext_vector_type(8)))  short  short8;   // 8 x bf16 frag
typedef __attribute__((ext_vector_type(16))) float  f32x16;   // 32x32 C/D frag
typedef __attribute__((ext_vector_type(8)))  ushort ushort8;

static __device__ __forceinline__ ushort f2bf(float f) {
    union { float f; unsigned u; } x; x.f = f;
    unsigned r = x.u + 0x7fffu + ((x.u >> 16) & 1u);   // RNE (no NaN inputs here)
    return (ushort)(r >> 16);
}

static __device__ __forceinline__ void gll16(const void* g, void* l) {
    __builtin_amdgcn_global_load_lds(
        (const __attribute__((address_space(1))) void*)g,
        (__attribute__((address_space(3))) void*)l, 16, 0, 0);
}

// ---------------------------------------------------------------------------
// Cast the three weight matrices to bf16 (all are 131072 elements).
// ---------------------------------------------------------------------------
__global__ __launch_bounds__(256) void cast_w(const float* __restrict__ a,
                                              const float* __restrict__ b,
                                              const float* __restrict__ c,
                                              ushort* __restrict__ da,
                                              ushort* __restrict__ db,
                                              ushort* __restrict__ dc)
{
    const int tid   = blockIdx.x * 256 + threadIdx.x;
    const int which = tid >> 14;                 // 16384 threads per matrix
    const int off   = (tid & 16383) * 8;
    const float* s = (which == 0) ? a : (which == 1) ? b : c;
    ushort*      d = (which == 0) ? da : (which == 1) ? db : dc;
    const float4 u = *(const float4*)(s + off);
    const float4 v = *(const float4*)(s + off + 4);
    ushort8 o;
    o[0] = f2bf(u.x); o[1] = f2bf(u.y); o[2] = f2bf(u.z); o[3] = f2bf(u.w);
    o[4] = f2bf(v.x); o[5] = f2bf(v.y); o[6] = f2bf(v.z); o[7] = f2bf(v.w);
    *(ushort8*)(d + off) = o;
}

// ---------------------------------------------------------------------------
// src fp32 [B][C][Nn] -> dst bf16 [B][Nn][C]  (LDS transpose, 64x64 tile)
// float4 reads (16B/lane), ushort8 writes (16B/lane).
// ---------------------------------------------------------------------------
__global__ __launch_bounds__(256) void transpose_c(const float* __restrict__ src,
                                                   ushort* __restrict__ dst, int C)
{
    const int b  = blockIdx.z;
    const int c0 = blockIdx.y * 64;
    const int n0 = blockIdx.x * 64;
    const int t  = threadIdx.x;
    __shared__ float T[64][65];
#pragma unroll
    for (int p = 0; p < 4; ++p) {                 // 1024 float4 loads
        const int flat = p * 256 + t;
        const int cc = flat >> 4, nn4 = (flat & 15) * 4;
        const float4 v = *(const float4*)(
            src + ((size_t)b * C + c0 + cc) * Nn + n0 + nn4);
        T[cc][nn4]     = v.x; T[cc][nn4 + 1] = v.y;
        T[cc][nn4 + 2] = v.z; T[cc][nn4 + 3] = v.w;
    }
    __syncthreads();
#pragma unroll
    for (int p = 0; p < 2; ++p) {                 // 512 ushort8 stores
        const int flat = p * 256 + t;
        const int nn = flat >> 3, cc0 = (flat & 7) * 8;
        ushort8 o;
#pragma unroll
        for (int i = 0; i < 8; ++i) o[i] = f2bf(T[cc0 + i][nn]);
        *(ushort8*)(dst + ((size_t)b * Nn + n0 + nn) * C + c0 + cc0) = o;
    }
}

// ---------------------------------------------------------------------------
// Fused QK/V GEMM (round-6 verified version — NO stats fusion):
//   qk[b][m][n]  = sum_k Wk[m][k] * XT[b][n][k] + bk[m]        (fp32)
//   val[b][m][n] = sum_k Wv[m][k] * XT[b][n][k] + bv[m]        (fp32 + bf16)
// ---------------------------------------------------------------------------
__global__ __launch_bounds__(256) void gemm_qv(const ushort* __restrict__ XT,
                                               const ushort* __restrict__ Wkb,
                                               const ushort* __restrict__ Wvb,
                                               const float*  __restrict__ bk,
                                               const float*  __restrict__ bv,
                                               float* __restrict__ qk,
                                               float* __restrict__ val,
                                               ushort* __restrict__ valB)
{
    const int b  = blockIdx.z;
    const int m0 = blockIdx.y * 128;
    const int n0 = blockIdx.x * 128;
    const int t  = threadIdx.x;
    const int w  = t >> 6, L = t & 63;
    const int l31 = L & 31, hl = L >> 5;
    const int wm = (w >> 1) * 64, wn = (w & 1) * 64;

    __shared__ __align__(16) short AsK[128][72];
    __shared__ __align__(16) short AsV[128][72];
    __shared__ __align__(16) short Bs[128][72];

    const ushort* Xb = XT + (size_t)b * Nn * Cin;

    f32x16 accK[2][2], accV[2][2];
#pragma unroll
    for (int a = 0; a < 2; ++a)
#pragma unroll
        for (int bb = 0; bb < 2; ++bb)
#pragma unroll
            for (int r = 0; r < 16; ++r) { accK[a][bb][r] = 0.f; accV[a][bb][r] = 0.f; }

    for (int k0 = 0; k0 < Cin; k0 += 64) {
        __syncthreads();
#pragma unroll
        for (int p = 0; p < 4; ++p) {            // stage Wk, Wv, xT tiles
            const int e   = p * 256 + t;
            const int row = e >> 3, ko = (e & 7) * 8;
            *(short8*)&AsK[row][ko] =
                *(const short8*)(Wkb + (size_t)(m0 + row) * Cin + k0 + ko);
            *(short8*)&AsV[row][ko] =
                *(const short8*)(Wvb + (size_t)(m0 + row) * Cin + k0 + ko);
            *(short8*)&Bs[row][ko] =
                *(const short8*)(Xb + (size_t)(n0 + row) * Cin + k0 + ko);
        }
        __syncthreads();
#pragma unroll
        for (int kc = 0; kc < 4; ++kc) {
            short8 Ak[2], Av[2], Bf[2];
#pragma unroll
            for (int a = 0; a < 2; ++a) {
                Ak[a] = *(const short8*)&AsK[wm + a * 32 + l31][kc * 16 + hl * 8];
                Av[a] = *(const short8*)&AsV[wm + a * 32 + l31][kc * 16 + hl * 8];
            }
#pragma unroll
            for (int bb = 0; bb < 2; ++bb)
                Bf[bb] = *(const short8*)&Bs[wn + bb * 32 + l31][kc * 16 + hl * 8];
#pragma unroll
            for (int a = 0; a < 2; ++a)
#pragma unroll
                for (int bb = 0; bb < 2; ++bb) {
                    accK[a][bb] = __builtin_amdgcn_mfma_f32_32x32x16_bf16(
                        Ak[a], Bf[bb], accK[a][bb], 0, 0, 0);
                    accV[a][bb] = __builtin_amdgcn_mfma_f32_32x32x16_bf16(
                        Av[a], Bf[bb], accV[a][bb], 0, 0, 0);
                }
        }
    }

    // epilogue: D row=(r&3)+8*(r>>2)+4*hl, col=l31
#pragma unroll
    for (int a = 0; a < 2; ++a)
#pragma unroll
        for (int r = 0; r < 16; ++r) {
            const int row = (r & 3) + 8 * (r >> 2) + 4 * hl;
            const int o   = m0 + wm + a * 32 + row;
            const float bkv = bk[o], bvv = bv[o];
            const size_t base = ((size_t)b * Ck + o) * Nn + n0 + wn + l31;
#pragma unroll
            for (int bb = 0; bb < 2; ++bb) {
                qk[base + bb * 32] = accK[a][bb][r] + bkv;
                const float vv = accV[a][bb][r] + bvv;
                val[base + bb * 32]  = vv;
                valB[base + bb * 32] = f2bf(vv);
            }
        }
}

// ---------------------------------------------------------------------------
// BN training stats (round-6 verified version)
// ---------------------------------------------------------------------------
__global__ __launch_bounds__(256) void bn_stats(const float* __restrict__ qk,
                                                const float* __restrict__ gamma,
                                                const float* __restrict__ beta,
                                                float* __restrict__ ss)
{
    const int o = blockIdx.x;
    const int t = threadIdx.x;
    float s = 0.f, sq = 0.f;
    for (int b = 0; b < Bn; ++b) {
        const float* p = qk + ((size_t)b * Ck + o) * Nn;
        for (int n = t * 4; n < Nn; n += 1024) {
            const float4 v = *(const float4*)(p + n);
            s  += v.x + v.y + v.z + v.w;
            sq += v.x * v.x + v.y * v.y + v.z * v.z + v.w * v.w;
        }
    }
    __shared__ float rs[256], rq[256];
    rs[t] = s; rq[t] = sq;
    __syncthreads();
    for (int off = 128; off > 0; off >>= 1) {
        if (t < off) { rs[t] += rs[t + off]; rq[t] += rq[t + off]; }
        __syncthreads();
    }
    if (t == 0) {
        const float cnt  = (float)(Bn * Nn);
        const float mean = rs[0] / cnt;
        const float var  = rq[0] / cnt - mean * mean;
        const float inv  = rsqrtf(var + 1e-5f);
        const float sc   = gamma[o] * inv;
        ss[o]       = sc;
        ss[256 + o] = beta[o] - mean * sc;
    }
}

// ---------------------------------------------------------------------------
// Fused BN-apply + ReLU + channel transpose (round-6 verified version):
//   reads qk (f1 slot), writes f1/f2 fp32 (coalesced) AND featT bf16 via LDS.
// ---------------------------------------------------------------------------
__global__ __launch_bounds__(256) void bn_relu_t(const float* __restrict__ qk,
                                                 const float* __restrict__ ss,
                                                 float* __restrict__ f1,
                                                 float* __restrict__ f2,
                                                 ushort* __restrict__ featT)
{
    const int b  = blockIdx.z;
    const int c0 = blockIdx.y * 64;
    const int n0 = blockIdx.x * 64;
    const int t  = threadIdx.x;
    __shared__ float T[64][65];
#pragma unroll
    for (int p = 0; p < 4; ++p) {                 // float4 load + BN + relu
        const int flat = p * 256 + t;
        const int cc = flat >> 4, nn4 = (flat & 15) * 4;
        const size_t gidx = ((size_t)b * Ck + c0 + cc) * Nn + n0 + nn4;
        const float sc = ss[c0 + cc], sh = ss[256 + c0 + cc];
        const float4 v = *(const float4*)(qk + gidx);
        float4 r;
        r.x = fmaxf(v.x * sc + sh, 0.f);
        r.y = fmaxf(v.y * sc + sh, 0.f);
        r.z = fmaxf(v.z * sc + sh, 0.f);
        r.w = fmaxf(v.w * sc + sh, 0.f);
        *(float4*)(f1 + gidx) = r;
        *(float4*)(f2 + gidx) = r;
        T[cc][nn4]     = r.x; T[cc][nn4 + 1] = r.y;
        T[cc][nn4 + 2] = r.z; T[cc][nn4 + 3] = r.w;
    }
    __syncthreads();
#pragma unroll
    for (int p = 0; p < 2; ++p) {                 // transposed ushort8 stores
        const int flat = p * 256 + t;
        const int nn = flat >> 3, cc0 = (flat & 7) * 8;
        ushort8 o;
#pragma unroll
        for (int i = 0; i < 8; ++i) o[i] = f2bf(T[cc0 + i][nn]);
        *(ushort8*)(featT + ((size_t)b * Nn + n0 + nn) * Ck + c0 + cc0) = o;
    }
}

// ---------------------------------------------------------------------------
// bf16 MFMA flash attention, no-max softmax (scores >= 0, <= ~33).
//   featT [B][Nn][Ck] bf16, valB [B][Cv][Nn] bf16, ctx OUT bf16 [B][Nn][Cv]
//
// Round-8: TLP fix — 2 independent blocks per CU.
//   Round-7 falsifier fired: attn is serialization-bound (LDS 2800 + VALU
//   2400 + MFMA 512 cyc/tile ADD to the measured 6100 — phases don't
//   overlap with 1 lockstep block/CU at 46% LDS util). Fix: 64-i-row
//   blocks, 4 waves, single-buffered K/V -> LDS 74240 B -> 2 blocks/CU.
//   Per-block loop is the simple 3-barrier stage->QK->PV sequence; the two
//   co-resident blocks run phase-shifted, overlapping one block's VALU/
//   barrier-stall with the other's LDS/MFMA. Same-CU blocks share the
//   batch's K/V (same b) -> L2-friendly re-stage.
// Wave roles: QK (ig = w>>1 over 2 i-groups, ch = w&1 j-half); PV (cq = w
// cv-quarter, both iA i-groups, full 64 j): 16 ds_read : 16 MFMA each.
// Kept: swapped QK^T, cvt_pk pack, permlane32_swap, gll16 + per-row
// rotation, batch->XCD grid, setprio. __launch_bounds__(256,2) caps VGPR
// at 256 (demand ~210 -> no spill).
// LDS: K 32K + V 32K + P 8K + Lr 0.5K = 74240 B.
// ---------------------------------------------------------------------------
constexpr int LDS_BYTES = 74240;

__global__ __launch_bounds__(256, 2) void attn_mfma(const ushort* __restrict__ featT,
                                                    const ushort* __restrict__ valB,
                                                    ushort* __restrict__ ctx)
{
    extern __shared__ __align__(16) char lds[];
    char* ldsK = lds;              // [64 rows][512 B]  (rotated image)
    char* ldsV = lds + 32768;      // [256 rows][128 B] (rotated image)
    char* ldsP = lds + 65536;      // [ig 2][jb 4][hl 2][32 lanes x 16 B]
    float* Lr  = (float*)(lds + 73728);   // [ig 2][ch 2][32]

    const int b   = blockIdx.x;                  // batch -> XCD affinity
    const int i0  = blockIdx.y * 64;
    const int t   = threadIdx.x;
    const int w   = t >> 6;
    const int L   = t & 63;
    const int l31 = L & 31, hl = L >> 5;
    const int ig  = w >> 1;                      // QK: i-group 0..1 (32 rows)
    const int ch  = w & 1;                       // QK: j-half owner
    const int cq  = w;                           // PV: cv-quarter 0..3 (64 cv)
    const int jsel = ch * 32;

    // read-side rotation bases (verified rounds 3-7)
    const int rbK  = hl * 16 + (((jsel + l31) << 4) & 511);
    const int rotV = (l31 << 4) & 127;

    const ushort* F = featT + (size_t)b * Nn * Ck;
    const ushort* V = valB  + (size_t)b * Cv * Nn;

    constexpr float CEXP = 0.09016844005556021f;  // log2(e)/16
    constexpr int NT = Nn / 64;                   // 64 j-tiles

    // Q fragments: rows i0 + ig*32 + l31
    short8 Qf[16];
    {
        const ushort* qp = F + ((size_t)(i0 + ig * 32 + l31)) * Ck + hl * 8;
#pragma unroll
        for (int kc = 0; kc < 16; ++kc)
            Qf[kc] = *(const short8*)(qp + kc * 16);
    }

    f32x16 Oacc[4];                               // [iA*2 + cvB]
#pragma unroll
    for (int c = 0; c < 4; ++c)
#pragma unroll
        for (int r = 0; r < 16; ++r) Oacc[c][r] = 0.f;
    float lsum = 0.f;

    const char* KgBase = (const char*)F;          // advances 32768 B / tile
    const char* VgBase = (const char*)V;          // advances 128 B / tile

    for (int jt = 0; jt < NT; ++jt) {
        // ---- stage K(jt) 32KB + V(jt) 32KB, 16 gll16/thread ----
#pragma unroll
        for (int p = 0; p < 8; ++p) {
            const int o  = (p * 256 + t) * 16;
            const int rK = o >> 9;
            gll16(KgBase + rK * 512 + ((o - rK * 16) & 511), ldsK + o);
        }
#pragma unroll
        for (int p = 0; p < 8; ++p) {
            const int o  = (p * 256 + t) * 16;
            const int rV = o >> 7;
            gll16(VgBase + (size_t)rV * (Nn * 2) + ((o - rV * 16) & 127),
                  ldsV + o);
        }
        asm volatile("s_waitcnt vmcnt(0)" ::: "memory");
        __builtin_amdgcn_s_barrier();             // barrier 1: K/V ready

        // ---- QK: S^T[j][i] for (ig, ch) ----
        const char* Kr = ldsK + (jsel + l31) * 512;
        f32x16 Sa, Sb;
#pragma unroll
        for (int r = 0; r < 16; ++r) { Sa[r] = 0.f; Sb[r] = 0.f; }
        __builtin_amdgcn_s_setprio(1);
#pragma unroll
        for (int kc = 0; kc < 8; ++kc) {
            const short8 K0 = *(const short8*)(Kr + ((kc * 64      + rbK) & 511));
            const short8 K1 = *(const short8*)(Kr + ((kc * 64 + 32 + rbK) & 511));
            Sa = __builtin_amdgcn_mfma_f32_32x32x16_bf16(K0, Qf[2 * kc],     Sa, 0, 0, 0);
            Sb = __builtin_amdgcn_mfma_f32_32x32x16_bf16(K1, Qf[2 * kc + 1], Sb, 0, 0, 0);
        }
        __builtin_amdgcn_s_setprio(0);

        // ---- softmax: exp + cvt_pk (hw RNE) + unrounded lsum ----
        unsigned pw[8];
#pragma unroll
        for (int r2 = 0; r2 < 8; ++r2) {
            const float p0 = exp2f((Sa[2 * r2]     + Sb[2 * r2])     * CEXP);
            const float p1 = exp2f((Sa[2 * r2 + 1] + Sb[2 * r2 + 1]) * CEXP);
            lsum += p0 + p1;
            unsigned pk;
            asm("v_cvt_pk_bf16_f32 %0, %1, %2" : "=v"(pk) : "v"(p0), "v"(p1));
            pw[r2] = pk;
        }
        {
            char* Pw = ldsP + ((ig * 4 + ch * 2) * 2 + hl) * 512 + l31 * 16;
#pragma unroll
            for (int g = 0; g < 2; ++g) {
                auto s02 = __builtin_amdgcn_permlane32_swap(pw[4 * g + 0], pw[4 * g + 2],
                                                            false, false);
                auto s13 = __builtin_amdgcn_permlane32_swap(pw[4 * g + 1], pw[4 * g + 3],
                                                            false, false);
                union { unsigned u[4]; short8 s; } pu;
                pu.u[0] = s02[0]; pu.u[1] = s13[0]; pu.u[2] = s02[1]; pu.u[3] = s13[1];
                *(short8*)(Pw + g * 1024) = pu.s;
            }
        }
        asm volatile("s_waitcnt lgkmcnt(0)" ::: "memory");
        __builtin_amdgcn_s_barrier();             // barrier 2: P ready

        // ---- PV: wave cq — 64 i x 64 cv x full 64 j ----
        {
            const char* Vb2 = ldsV + (cq * 64 + l31) * 128;
            const char* Pb  = ldsP + hl * 512 + l31 * 16;
            __builtin_amdgcn_s_setprio(1);
#pragma unroll
            for (int jb = 0; jb < 4; ++jb) {
                short8 Pa[2];
#pragma unroll
                for (int iA = 0; iA < 2; ++iA)
                    Pa[iA] = *(const short8*)(Pb + (iA * 4 + jb) * 1024);
                const int jbyte = jb * 32 + hl * 16;
#pragma unroll
                for (int cvB = 0; cvB < 2; ++cvB) {
                    const short8 Vf = *(const short8*)(Vb2 + cvB * 4096
                                         + ((jbyte + rotV) & 127));
#pragma unroll
                    for (int iA = 0; iA < 2; ++iA)
                        Oacc[iA * 2 + cvB] = __builtin_amdgcn_mfma_f32_32x32x16_bf16(
                            Pa[iA], Vf, Oacc[iA * 2 + cvB], 0, 0, 0);
                }
            }
            __builtin_amdgcn_s_setprio(0);
        }
        asm volatile("s_waitcnt lgkmcnt(0)" ::: "memory");
        __builtin_amdgcn_s_barrier();             // barrier 3: K/V/P free

        KgBase += 32768;                          // 64 rows x 512 B
        VgBase += 128;                            // 64 j x 2 B
    }

    // ---- l merge (hl in-reg, ch via LDS) ----
    {
        unsigned a = __float_as_uint(lsum), bcopy = a;
        auto sw = __builtin_amdgcn_permlane32_swap(a, bcopy, false, false);
        lsum = __uint_as_float(sw[0]) + __uint_as_float(sw[1]);
    }
    Lr[(ig * 2 + ch) * 32 + l31] = lsum;
    asm volatile("s_waitcnt lgkmcnt(0)" ::: "memory");
    __builtin_amdgcn_s_barrier();

    // store: wave owns rows i0 + iA*32 + row, cols cq*64 + cvB*32 + l31
    ushort* Cb = ctx + ((size_t)b * Nn + i0) * Cv + cq * 64;
#pragma unroll
    for (int iA = 0; iA < 2; ++iA) {
#pragma unroll
        for (int r = 0; r < 16; ++r) {
            const int row = (r & 3) + 8 * (r >> 2) + 4 * hl;
            const float lt = Lr[(iA * 2) * 32 + row] + Lr[(iA * 2 + 1) * 32 + row];
            const float linv = 1.f / lt;
            ushort* cp = Cb + (size_t)(iA * 32 + row) * Cv + l31;
#pragma unroll
            for (int cvB = 0; cvB < 2; ++cvB)
                cp[cvB * 32] = f2bf(Oacc[iA * 2 + cvB][r] * linv);
        }
    }
}

// ---------------------------------------------------------------------------
// Final 1x1 conv GEMM (unchanged structure):
//   out[b][m][n] = sum_k Wb[m][k] * XT[b][n][k] + bias[m]
// ---------------------------------------------------------------------------
template <int K>
__global__ __launch_bounds__(256) void gemm_bf(const ushort* __restrict__ XT,
                                               const ushort* __restrict__ Wb,
                                               const float*  __restrict__ bias,
                                               float* __restrict__ out,
                                               int M)
{
    const int b  = blockIdx.z;
    const int m0 = blockIdx.y * 128;
    const int n0 = blockIdx.x * 128;
    const int t  = threadIdx.x;
    const int w  = t >> 6, L = t & 63;
    const int l31 = L & 31, hl = L >> 5;
    const int wm = (w >> 1) * 64, wn = (w & 1) * 64;

    __shared__ __align__(16) short As[128][72];   // [m][k]
    __shared__ __align__(16) short Bs[128][72];   // [n][k]

    const ushort* Xb = XT + (size_t)b * Nn * K;

    f32x16 acc[2][2];
#pragma unroll
    for (int a = 0; a < 2; ++a)
#pragma unroll
        for (int bb = 0; bb < 2; ++bb)
#pragma unroll
            for (int r = 0; r < 16; ++r) acc[a][bb][r] = 0.f;

    for (int k0 = 0; k0 < K; k0 += 64) {
        __syncthreads();
#pragma unroll
        for (int p = 0; p < 4; ++p) {            // stage 128x64 A and B tiles
            const int e   = p * 256 + t;
            const int row = e >> 3, ko = (e & 7) * 8;
            *(short8*)&As[row][ko] =
                *(const short8*)(Wb + (size_t)(m0 + row) * K + k0 + ko);
            *(short8*)&Bs[row][ko] =
                *(const short8*)(Xb + (size_t)(n0 + row) * K + k0 + ko);
        }
        __syncthreads();
#pragma unroll
        for (int kc = 0; kc < 4; ++kc) {
            short8 Af[2], Bf[2];
#pragma unroll
            for (int a = 0; a < 2; ++a)
                Af[a] = *(const short8*)&As[wm + a * 32 + l31][kc * 16 + hl * 8];
#pragma unroll
            for (int bb = 0; bb < 2; ++bb)
                Bf[bb] = *(const short8*)&Bs[wn + bb * 32 + l31][kc * 16 + hl * 8];
#pragma unroll
            for (int a = 0; a < 2; ++a)
#pragma unroll
                for (int bb = 0; bb < 2; ++bb)
                    acc[a][bb] = __builtin_amdgcn_mfma_f32_32x32x16_bf16(
                        Af[a], Bf[bb], acc[a][bb], 0, 0, 0);
        }
    }

    // epilogue: D row=(r&3)+8*(r>>2)+4*hl, col=l31
#pragma unroll
    for (int a = 0; a < 2; ++a)
#pragma unroll
        for (int r = 0; r < 16; ++r) {
            const int row = (r & 3) + 8 * (r >> 2) + 4 * hl;
            const int o   = m0 + wm + a * 32 + row;
            const float bv = bias[o];
            const size_t base = ((size_t)b * M + o) * Nn + n0 + wn + l31;
#pragma unroll
            for (int bb = 0; bb < 2; ++bb)
                out[base + bb * 32] = acc[a][bb][r] + bv;
        }
}

// ---------------------------------------------------------------------------
extern "C" void kernel_launch(void* const* d_in, const int* in_sizes, int n_in,
                              void* d_out, int out_size, void* d_ws, size_t ws_size,
                              hipStream_t stream)
{
    const float* x     = (const float*)d_in[0];
    const float* Wk    = (const float*)d_in[1];
    const float* bk    = (const float*)d_in[2];
    const float* gamma = (const float*)d_in[3];
    const float* beta  = (const float*)d_in[4];
    const float* Wv    = (const float*)d_in[5];
    const float* bv    = (const float*)d_in[6];
    const float* Ww    = (const float*)d_in[7];
    const float* bw    = (const float*)d_in[8];

    float* out = (float*)d_out;
    float* f1  = out + F1_OFF;
    float* f2  = out + F2_OFF;
    float* val = out + VAL_OFF;

    // workspace packing (51.1 MB), with aliasing over dead xT:
    //   xT    : [0 .. 16,777,216) ushorts   live steps 2-3
    //   featT : alias xT[0 .. 8,388,608)    live steps 5-6
    //   ctxb  : alias xT[8,388,608 .. )     live steps 6-7
    ushort* xT    = (ushort*)d_ws;                       // [B][Nn][Cin]
    ushort* featT = xT;                                  // [B][Nn][Ck]
    ushort* ctxb  = xT + (size_t)8388608;                // [B][Nn][Cv]
    ushort* valB  = xT + (size_t)16777216;               // [B][Cv][Nn]
    ushort* Wkb   = valB + (size_t)8388608;
    ushort* Wvb   = Wkb + 131072;
    ushort* Wwb   = Wvb + 131072;
    float*  ss    = (float*)(Wwb + 131072);              // 512 floats

    // one-time: allow 74240 B dynamic LDS for the attention kernel
    static bool attn_attr_set = false;
    if (!attn_attr_set) {
        (void)hipFuncSetAttribute((const void*)attn_mfma,
                                  hipFuncAttributeMaxDynamicSharedMemorySize,
                                  LDS_BYTES);
        attn_attr_set = true;
    }

    // 1) weights -> bf16
    cast_w<<<192, 256, 0, stream>>>(Wk, Wv, Ww, Wkb, Wvb, Wwb);
    // 2) x -> xT bf16 [B][Nn][Cin]
    transpose_c<<<dim3(Nn / 64, Cin / 64, Bn), 256, 0, stream>>>(x, xT, Cin);
    // 3) fused: qk = Wk*x + bk (fp32) AND value = Wv*x + bv (fp32 + bf16)
    gemm_qv<<<dim3(Nn / 128, Ck / 128, Bn), 256, 0, stream>>>(
        xT, Wkb, Wvb, bk, bv, f1, val, valB);
    // 4) BN stats
    bn_stats<<<Ck, 256, 0, stream>>>(f1, gamma, beta, ss);
    // 5) fused: feat = relu(norm(qk)) -> f1, f2 AND featT bf16 (xT dead)
    bn_relu_t<<<dim3(Nn / 64, Ck / 64, Bn), 256, 0, stream>>>(
        f1, ss, f1, f2, featT);
    // 6) flash attention -> ctx bf16 [B][Nn][Cv], 512 blocks = 2/CU
    attn_mfma<<<dim3(Bn, Nn / 64), 256, LDS_BYTES, stream>>>(featT, valB, ctxb);
    // 7) out = Ww*ctx + bw
    gemm_bf<256><<<dim3(Nn / 128, Co / 128, Bn), 256, 0, stream>>>(
        ctxb, Wwb, bw, out, Co);
}

// Round 9
// 444.370 us; speedup vs baseline: 1.1935x; 1.0334x over previous
//
#include <hip/hip_runtime.h>
#include <math.h>

// Problem constants (from reference setup_inputs)
constexpr int  Bn  = 8;        // batch
constexpr int  Cin = 512;      // input channels
constexpr int  Nn  = 4096;     // H*W
constexpr int  Ck  = 256;      // key/query channels
constexpr int  Cv  = 256;      // value channels
constexpr int  Co  = 512;      // output channels

// d_out layout: [out | feat | feat | value]
constexpr size_t F1_OFF  = (size_t)Bn * Co * Nn;
constexpr size_t F2_OFF  = F1_OFF + (size_t)Bn * Ck * Nn;
constexpr size_t VAL_OFF = F2_OFF + (size_t)Bn * Ck * Nn;

typedef __attribute__((ext_vector_type(8)))  short  short8;   // 8 x bf16 frag
typedef __attribute__((ext_vector_type(16))) float  f32x16;   // 32x32 C/D frag
typedef __attribute__((ext_vector_type(8)))  ushort ushort8;

static __device__ __forceinline__ ushort f2bf(float f) {
    union { float f; unsigned u; } x; x.f = f;
    unsigned r = x.u + 0x7fffu + ((x.u >> 16) & 1u);   // RNE (no NaN inputs here)
    return (ushort)(r >> 16);
}

static __device__ __forceinline__ void gll16(const void* g, void* l) {
    __builtin_amdgcn_global_load_lds(
        (const __attribute__((address_space(1))) void*)g,
        (__attribute__((address_space(3))) void*)l, 16, 0, 0);
}

// ---------------------------------------------------------------------------
// Cast the three weight matrices to bf16 (all are 131072 elements).
// ---------------------------------------------------------------------------
__global__ __launch_bounds__(256) void cast_w(const float* __restrict__ a,
                                              const float* __restrict__ b,
                                              const float* __restrict__ c,
                                              ushort* __restrict__ da,
                                              ushort* __restrict__ db,
                                              ushort* __restrict__ dc)
{
    const int tid   = blockIdx.x * 256 + threadIdx.x;
    const int which = tid >> 14;                 // 16384 threads per matrix
    const int off   = (tid & 16383) * 8;
    const float* s = (which == 0) ? a : (which == 1) ? b : c;
    ushort*      d = (which == 0) ? da : (which == 1) ? db : dc;
    const float4 u = *(const float4*)(s + off);
    const float4 v = *(const float4*)(s + off + 4);
    ushort8 o;
    o[0] = f2bf(u.x); o[1] = f2bf(u.y); o[2] = f2bf(u.z); o[3] = f2bf(u.w);
    o[4] = f2bf(v.x); o[5] = f2bf(v.y); o[6] = f2bf(v.z); o[7] = f2bf(v.w);
    *(ushort8*)(d + off) = o;
}

// ---------------------------------------------------------------------------
// src fp32 [B][C][Nn] -> dst bf16 [B][Nn][C]  (LDS transpose, 64x64 tile)
// float4 reads (16B/lane), ushort8 writes (16B/lane).
// ---------------------------------------------------------------------------
__global__ __launch_bounds__(256) void transpose_c(const float* __restrict__ src,
                                                   ushort* __restrict__ dst, int C)
{
    const int b  = blockIdx.z;
    const int c0 = blockIdx.y * 64;
    const int n0 = blockIdx.x * 64;
    const int t  = threadIdx.x;
    __shared__ float T[64][65];
#pragma unroll
    for (int p = 0; p < 4; ++p) {                 // 1024 float4 loads
        const int flat = p * 256 + t;
        const int cc = flat >> 4, nn4 = (flat & 15) * 4;
        const float4 v = *(const float4*)(
            src + ((size_t)b * C + c0 + cc) * Nn + n0 + nn4);
        T[cc][nn4]     = v.x; T[cc][nn4 + 1] = v.y;
        T[cc][nn4 + 2] = v.z; T[cc][nn4 + 3] = v.w;
    }
    __syncthreads();
#pragma unroll
    for (int p = 0; p < 2; ++p) {                 // 512 ushort8 stores
        const int flat = p * 256 + t;
        const int nn = flat >> 3, cc0 = (flat & 7) * 8;
        ushort8 o;
#pragma unroll
        for (int i = 0; i < 8; ++i) o[i] = f2bf(T[cc0 + i][nn]);
        *(ushort8*)(dst + ((size_t)b * Nn + n0 + nn) * C + c0 + cc0) = o;
    }
}

// ---------------------------------------------------------------------------
// Fused QK/V GEMM — round-9: global_load_lds staging (ladder m93->m97 lever).
//   Tiles [128 rows][64 k] bf16 = 128 B rows, stored ROTATED (16B x row,
//   the attn-V-verified both-sides pattern): linear LDS dest, inverse-
//   rotated global source, rotated read. No ds_writes, no staging VGPRs.
//   qk[b][m][n]  = sum_k Wk[m][k] * XT[b][n][k] + bk[m]        (fp32)
//   val[b][m][n] = sum_k Wv[m][k] * XT[b][n][k] + bv[m]        (fp32 + bf16)
// ---------------------------------------------------------------------------
__global__ __launch_bounds__(256) void gemm_qv(const ushort* __restrict__ XT,
                                               const ushort* __restrict__ Wkb,
                                               const ushort* __restrict__ Wvb,
                                               const float*  __restrict__ bk,
                                               const float*  __restrict__ bv,
                                               float* __restrict__ qk,
                                               float* __restrict__ val,
                                               ushort* __restrict__ valB)
{
    __shared__ __align__(16) char smem[49152];    // AsK | AsV | Bs (16KB each)
    char* AsK = smem;
    char* AsV = smem + 16384;
    char* Bs  = smem + 32768;

    const int b  = blockIdx.z;
    const int m0 = blockIdx.y * 128;
    const int n0 = blockIdx.x * 128;
    const int t  = threadIdx.x;
    const int w  = t >> 6, L = t & 63;
    const int l31 = L & 31, hl = L >> 5;
    const int wm = (w >> 1) * 64, wn = (w & 1) * 64;

    const char* WkG = (const char*)(Wkb + (size_t)m0 * Cin);
    const char* WvG = (const char*)(Wvb + (size_t)m0 * Cin);
    const char* XbG = (const char*)(XT + ((size_t)b * Nn + n0) * Cin);

    f32x16 accK[2][2], accV[2][2];
#pragma unroll
    for (int a = 0; a < 2; ++a)
#pragma unroll
        for (int bb = 0; bb < 2; ++bb)
#pragma unroll
            for (int r = 0; r < 16; ++r) { accK[a][bb][r] = 0.f; accV[a][bb][r] = 0.f; }

    for (int k0 = 0; k0 < Cin; k0 += 64) {
        __syncthreads();
        const int kb = k0 * 2;                    // k-tile byte offset in row
#pragma unroll
        for (int p = 0; p < 4; ++p) {             // 4KB per round x 4 x 3 mats
            const int o   = (p * 256 + t) * 16;   // linear LDS offset
            const int row = o >> 7;
            const int src = kb + ((o - (row << 4)) & 127);  // inverse-rotated
            gll16(WkG + (size_t)row * 1024 + src, AsK + o);
            gll16(WvG + (size_t)row * 1024 + src, AsV + o);
            gll16(XbG + (size_t)row * 1024 + src, Bs  + o);
        }
        asm volatile("s_waitcnt vmcnt(0)" ::: "memory");
        __syncthreads();
#pragma unroll
        for (int kc = 0; kc < 4; ++kc) {
            short8 Ak[2], Av[2], Bf[2];
#pragma unroll
            for (int a = 0; a < 2; ++a) {
                const int row = wm + a * 32 + l31;
                const int off = (kc * 32 + hl * 16 + (row << 4)) & 127;
                Ak[a] = *(const short8*)(AsK + row * 128 + off);
                Av[a] = *(const short8*)(AsV + row * 128 + off);
            }
#pragma unroll
            for (int bb = 0; bb < 2; ++bb) {
                const int row = wn + bb * 32 + l31;
                const int off = (kc * 32 + hl * 16 + (row << 4)) & 127;
                Bf[bb] = *(const short8*)(Bs + row * 128 + off);
            }
#pragma unroll
            for (int a = 0; a < 2; ++a)
#pragma unroll
                for (int bb = 0; bb < 2; ++bb) {
                    accK[a][bb] = __builtin_amdgcn_mfma_f32_32x32x16_bf16(
                        Ak[a], Bf[bb], accK[a][bb], 0, 0, 0);
                    accV[a][bb] = __builtin_amdgcn_mfma_f32_32x32x16_bf16(
                        Av[a], Bf[bb], accV[a][bb], 0, 0, 0);
                }
        }
    }

    // epilogue: D row=(r&3)+8*(r>>2)+4*hl, col=l31
#pragma unroll
    for (int a = 0; a < 2; ++a)
#pragma unroll
        for (int r = 0; r < 16; ++r) {
            const int row = (r & 3) + 8 * (r >> 2) + 4 * hl;
            const int o   = m0 + wm + a * 32 + row;
            const float bkv = bk[o], bvv = bv[o];
            const size_t base = ((size_t)b * Ck + o) * Nn + n0 + wn + l31;
#pragma unroll
            for (int bb = 0; bb < 2; ++bb) {
                qk[base + bb * 32] = accK[a][bb][r] + bkv;
                const float vv = accV[a][bb][r] + bvv;
                val[base + bb * 32]  = vv;
                valB[base + bb * 32] = f2bf(vv);
            }
        }
}

// ---------------------------------------------------------------------------
// BN training stats (round-6 verified version)
// ---------------------------------------------------------------------------
__global__ __launch_bounds__(256) void bn_stats(const float* __restrict__ qk,
                                                const float* __restrict__ gamma,
                                                const float* __restrict__ beta,
                                                float* __restrict__ ss)
{
    const int o = blockIdx.x;
    const int t = threadIdx.x;
    float s = 0.f, sq = 0.f;
    for (int b = 0; b < Bn; ++b) {
        const float* p = qk + ((size_t)b * Ck + o) * Nn;
        for (int n = t * 4; n < Nn; n += 1024) {
            const float4 v = *(const float4*)(p + n);
            s  += v.x + v.y + v.z + v.w;
            sq += v.x * v.x + v.y * v.y + v.z * v.z + v.w * v.w;
        }
    }
    __shared__ float rs[256], rq[256];
    rs[t] = s; rq[t] = sq;
    __syncthreads();
    for (int off = 128; off > 0; off >>= 1) {
        if (t < off) { rs[t] += rs[t + off]; rq[t] += rq[t + off]; }
        __syncthreads();
    }
    if (t == 0) {
        const float cnt  = (float)(Bn * Nn);
        const float mean = rs[0] / cnt;
        const float var  = rq[0] / cnt - mean * mean;
        const float inv  = rsqrtf(var + 1e-5f);
        const float sc   = gamma[o] * inv;
        ss[o]       = sc;
        ss[256 + o] = beta[o] - mean * sc;
    }
}

// ---------------------------------------------------------------------------
// Fused BN-apply + ReLU + channel transpose (round-6 verified version):
//   reads qk (f1 slot), writes f1/f2 fp32 (coalesced) AND featT bf16 via LDS.
// ---------------------------------------------------------------------------
__global__ __launch_bounds__(256) void bn_relu_t(const float* __restrict__ qk,
                                                 const float* __restrict__ ss,
                                                 float* __restrict__ f1,
                                                 float* __restrict__ f2,
                                                 ushort* __restrict__ featT)
{
    const int b  = blockIdx.z;
    const int c0 = blockIdx.y * 64;
    const int n0 = blockIdx.x * 64;
    const int t  = threadIdx.x;
    __shared__ float T[64][65];
#pragma unroll
    for (int p = 0; p < 4; ++p) {                 // float4 load + BN + relu
        const int flat = p * 256 + t;
        const int cc = flat >> 4, nn4 = (flat & 15) * 4;
        const size_t gidx = ((size_t)b * Ck + c0 + cc) * Nn + n0 + nn4;
        const float sc = ss[c0 + cc], sh = ss[256 + c0 + cc];
        const float4 v = *(const float4*)(qk + gidx);
        float4 r;
        r.x = fmaxf(v.x * sc + sh, 0.f);
        r.y = fmaxf(v.y * sc + sh, 0.f);
        r.z = fmaxf(v.z * sc + sh, 0.f);
        r.w = fmaxf(v.w * sc + sh, 0.f);
        *(float4*)(f1 + gidx) = r;
        *(float4*)(f2 + gidx) = r;
        T[cc][nn4]     = r.x; T[cc][nn4 + 1] = r.y;
        T[cc][nn4 + 2] = r.z; T[cc][nn4 + 3] = r.w;
    }
    __syncthreads();
#pragma unroll
    for (int p = 0; p < 2; ++p) {                 // transposed ushort8 stores
        const int flat = p * 256 + t;
        const int nn = flat >> 3, cc0 = (flat & 7) * 8;
        ushort8 o;
#pragma unroll
        for (int i = 0; i < 8; ++i) o[i] = f2bf(T[cc0 + i][nn]);
        *(ushort8*)(featT + ((size_t)b * Nn + n0 + nn) * Ck + c0 + cc0) = o;
    }
}

// ---------------------------------------------------------------------------
// bf16 MFMA flash attention — ROUND-7 VERIFIED VERSION (162 µs), unchanged.
//   1-barrier pipeline, QK(s)//PV(s-1), i2cv4 PV split, swapped QK^T,
//   cvt_pk pack, permlane32_swap, gll16 + per-row rotation, batch->XCD grid.
// LDS: K 2x32K + V 2x32K + P 2x16K = 163840 B.
// ---------------------------------------------------------------------------
constexpr int ATTN_LDS_BYTES = 163840;

__global__ __launch_bounds__(512) void attn_mfma(const ushort* __restrict__ featT,
                                                 const ushort* __restrict__ valB,
                                                 ushort* __restrict__ ctx)
{
    extern __shared__ __align__(16) char lds[];
    char* ldsK = lds;              // [buf][64 rows][512 B]  (rotated image)
    char* ldsV = lds + 65536;      // [buf][256 rows][128 B] (rotated image)
    char* ldsP = lds + 131072;     // [buf][IG 4][jb 4][hl 2][32 lanes x 16 B]

    const int b   = blockIdx.x;                  // batch -> XCD affinity
    const int i0  = blockIdx.y * 128;
    const int t   = threadIdx.x;
    const int w   = t >> 6;
    const int L   = t & 63;
    const int l31 = L & 31, hl = L >> 5;
    const int ig  = w >> 1;                      // QK: i-group 0..3 (32 rows)
    const int ch  = w & 1;                       // QK: j-half owner
    const int iq  = w >> 2;                      // PV: i-half 0..1 (64 rows)
    const int cq  = w & 3;                       // PV: cv-quarter 0..3 (64 cv)
    const int jsel = ch * 32;

    const int rbK  = hl * 16 + (((jsel + l31) << 4) & 511);
    const int rotV = (l31 << 4) & 127;

    const ushort* F = featT + (size_t)b * Nn * Ck;
    const ushort* V = valB  + (size_t)b * Cv * Nn;
    const char*   Vg = (const char*)V;

    constexpr float CEXP = 0.09016844005556021f;  // log2(e)/16
    constexpr int NT = Nn / 64;                   // 64 j-tiles

#define STAGE_K(J0, BUF) do {                                                  \
        const char* Kg_ = (const char*)(F + (size_t)(J0) * Ck);                \
        char* Kd_ = ldsK + (BUF) * 32768;                                      \
        _Pragma("unroll")                                                      \
        for (int p_ = 0; p_ < 4; ++p_) {                                       \
            const int c_ = w * 4 + p_;                                         \
            const int o_ = c_ * 1024 + L * 16;                                 \
            const int rK_ = o_ >> 9;                                           \
            gll16(Kg_ + rK_ * 512 + ((o_ - rK_ * 16) & 511), Kd_ + c_ * 1024); \
        }                                                                      \
    } while (0)

#define STAGE_V(J0, BUF) do {                                                  \
        char* Vd_ = ldsV + (BUF) * 32768;                                      \
        _Pragma("unroll")                                                      \
        for (int p_ = 0; p_ < 4; ++p_) {                                       \
            const int c_ = w * 4 + p_;                                         \
            const int o_ = c_ * 1024 + L * 16;                                 \
            const int rV_ = o_ >> 7;                                           \
            gll16(Vg + (size_t)rV_ * (Nn * 2) + (size_t)(J0) * 2               \
                     + ((o_ - rV_ * 16) & 127), Vd_ + c_ * 1024);              \
        }                                                                      \
    } while (0)

    // prologue: K(0) staged; Q fragments; drain + align all waves
    STAGE_K(0, 0);
    short8 Qf[16];
    {
        const ushort* qp = F + ((size_t)(i0 + ig * 32 + l31)) * Ck + hl * 8;
#pragma unroll
        for (int kc = 0; kc < 16; ++kc)
            Qf[kc] = *(const short8*)(qp + kc * 16);
    }
    asm volatile("s_waitcnt vmcnt(0)" ::: "memory");
    __builtin_amdgcn_s_barrier();

    f32x16 Oacc[4];                               // [iA*2 + cvB]
#pragma unroll
    for (int c = 0; c < 4; ++c)
#pragma unroll
        for (int r = 0; r < 16; ++r) Oacc[c][r] = 0.f;
    float lsum = 0.f;

    int cur = 0;
    for (int s = 0; s < NT; ++s) {
        // stage K(s+1) and V(s) — consumed next iteration
        const int jn = (s + 1 < NT ? s + 1 : NT - 1) * 64;
        STAGE_K(jn, cur ^ 1);
        STAGE_V((size_t)s * 64, cur);

        // ---- QK(s): S^T[j][i] from K[cur] ----
        const char* Kr = ldsK + cur * 32768 + (jsel + l31) * 512;
        f32x16 Sa, Sb;
#pragma unroll
        for (int r = 0; r < 16; ++r) { Sa[r] = 0.f; Sb[r] = 0.f; }
        __builtin_amdgcn_s_setprio(1);
#pragma unroll
        for (int kc = 0; kc < 8; ++kc) {
            const short8 K0 = *(const short8*)(Kr + ((kc * 64      + rbK) & 511));
            const short8 K1 = *(const short8*)(Kr + ((kc * 64 + 32 + rbK) & 511));
            Sa = __builtin_amdgcn_mfma_f32_32x32x16_bf16(K0, Qf[2 * kc],     Sa, 0, 0, 0);
            Sb = __builtin_amdgcn_mfma_f32_32x32x16_bf16(K1, Qf[2 * kc + 1], Sb, 0, 0, 0);
        }
        __builtin_amdgcn_s_setprio(0);

        // ---- PV(s-1): i2cv4 — 64 i x 64 cv, full j, from buf cur^1 ----
        if (s > 0) {
            const char* Vb2 = ldsV + (cur ^ 1) * 32768 + (cq * 64 + l31) * 128;
            const char* Pb  = ldsP + (cur ^ 1) * 16384 + hl * 512 + l31 * 16;
            __builtin_amdgcn_s_setprio(1);
#pragma unroll
            for (int jb = 0; jb < 4; ++jb) {
                short8 Pa[2];
#pragma unroll
                for (int iA = 0; iA < 2; ++iA)
                    Pa[iA] = *(const short8*)(Pb + ((iq * 2 + iA) * 4 + jb) * 1024);
                const int jbyte = jb * 32 + hl * 16;
#pragma unroll
                for (int cvB = 0; cvB < 2; ++cvB) {
                    const short8 Vf = *(const short8*)(Vb2 + cvB * 4096
                                         + ((jbyte + rotV) & 127));
#pragma unroll
                    for (int iA = 0; iA < 2; ++iA)
                        Oacc[iA * 2 + cvB] = __builtin_amdgcn_mfma_f32_32x32x16_bf16(
                            Pa[iA], Vf, Oacc[iA * 2 + cvB], 0, 0, 0);
                }
            }
            __builtin_amdgcn_s_setprio(0);
        }

        // ---- softmax: exp + cvt_pk (hw RNE) + unrounded lsum ----
        unsigned pw[8];
#pragma unroll
        for (int r2 = 0; r2 < 8; ++r2) {
            const float p0 = exp2f((Sa[2 * r2]     + Sb[2 * r2])     * CEXP);
            const float p1 = exp2f((Sa[2 * r2 + 1] + Sb[2 * r2 + 1]) * CEXP);
            lsum += p0 + p1;
            unsigned pk;
            asm("v_cvt_pk_bf16_f32 %0, %1, %2" : "=v"(pk) : "v"(p0), "v"(p1));
            pw[r2] = pk;
        }
        {
            char* Pw = ldsP + cur * 16384
                       + ((ig * 4 + ch * 2) * 2 + hl) * 512 + l31 * 16;
#pragma unroll
            for (int g = 0; g < 2; ++g) {
                auto s02 = __builtin_amdgcn_permlane32_swap(pw[4 * g + 0], pw[4 * g + 2],
                                                            false, false);
                auto s13 = __builtin_amdgcn_permlane32_swap(pw[4 * g + 1], pw[4 * g + 3],
                                                            false, false);
                union { unsigned u[4]; short8 s; } pu;
                pu.u[0] = s02[0]; pu.u[1] = s13[0]; pu.u[2] = s02[1]; pu.u[3] = s13[1];
                *(short8*)(Pw + g * 1024) = pu.s;
            }
        }

        // drain MY glls + ds ops, then align: everyone's staging visible
        asm volatile("s_waitcnt vmcnt(0) lgkmcnt(0)" ::: "memory");
        __builtin_amdgcn_s_barrier();
        cur ^= 1;
    }
#undef STAGE_K
#undef STAGE_V

    // ---- epilogue PV(NT-1): same i2cv4 pattern from buf cur^1 ----
    {
        const char* Vb2 = ldsV + (cur ^ 1) * 32768 + (cq * 64 + l31) * 128;
        const char* Pb  = ldsP + (cur ^ 1) * 16384 + hl * 512 + l31 * 16;
#pragma unroll
        for (int jb = 0; jb < 4; ++jb) {
            short8 Pa[2];
#pragma unroll
            for (int iA = 0; iA < 2; ++iA)
                Pa[iA] = *(const short8*)(Pb + ((iq * 2 + iA) * 4 + jb) * 1024);
            const int jbyte = jb * 32 + hl * 16;
#pragma unroll
            for (int cvB = 0; cvB < 2; ++cvB) {
                const short8 Vf = *(const short8*)(Vb2 + cvB * 4096
                                     + ((jbyte + rotV) & 127));
#pragma unroll
                for (int iA = 0; iA < 2; ++iA)
                    Oacc[iA * 2 + cvB] = __builtin_amdgcn_mfma_f32_32x32x16_bf16(
                        Pa[iA], Vf, Oacc[iA * 2 + cvB], 0, 0, 0);
            }
        }
    }

    // ---- l merge (hl in-reg, ch via LDS; Lr aliases dead P buf 0) ----
    {
        unsigned a = __float_as_uint(lsum), bcopy = a;
        auto sw = __builtin_amdgcn_permlane32_swap(a, bcopy, false, false);
        lsum = __uint_as_float(sw[0]) + __uint_as_float(sw[1]);
    }
    float* Lr = (float*)ldsP;          // P buf0 dead (epilogue reads buf1)
    Lr[(ig * 2 + ch) * 32 + l31] = lsum;
    asm volatile("s_waitcnt lgkmcnt(0)" ::: "memory");
    __builtin_amdgcn_s_barrier();

    // store: wave owns rows i0 + iq*64 + iA*32 + row, cols cq*64 + cvB*32 + l31
    ushort* Cb = ctx + ((size_t)b * Nn + i0 + iq * 64) * Cv + cq * 64;
#pragma unroll
    for (int iA = 0; iA < 2; ++iA) {
        const int IG = iq * 2 + iA;
#pragma unroll
        for (int r = 0; r < 16; ++r) {
            const int row = (r & 3) + 8 * (r >> 2) + 4 * hl;
            const float lt = Lr[(IG * 2) * 32 + row] + Lr[(IG * 2 + 1) * 32 + row];
            const float linv = 1.f / lt;
            ushort* cp = Cb + (size_t)(iA * 32 + row) * Cv + l31;
#pragma unroll
            for (int cvB = 0; cvB < 2; ++cvB)
                cp[cvB * 32] = f2bf(Oacc[iA * 2 + cvB][r] * linv);
        }
    }
}

// ---------------------------------------------------------------------------
// Final 1x1 conv GEMM — round-9: global_load_lds staging + rotation, same
// both-sides pattern as gemm_qv. Tiles [128 rows][64 k] = 128 B rows.
//   out[b][m][n] = sum_k Wb[m][k] * XT[b][n][k] + bias[m]
// ---------------------------------------------------------------------------
template <int K>
__global__ __launch_bounds__(256) void gemm_bf(const ushort* __restrict__ XT,
                                               const ushort* __restrict__ Wb,
                                               const float*  __restrict__ bias,
                                               float* __restrict__ out,
                                               int M)
{
    __shared__ __align__(16) char smem[32768];    // As | Bs (16KB each)
    char* As = smem;
    char* Bs = smem + 16384;

    const int b  = blockIdx.z;
    const int m0 = blockIdx.y * 128;
    const int n0 = blockIdx.x * 128;
    const int t  = threadIdx.x;
    const int w  = t >> 6, L = t & 63;
    const int l31 = L & 31, hl = L >> 5;
    const int wm = (w >> 1) * 64, wn = (w & 1) * 64;

    const char* WG = (const char*)(Wb + (size_t)m0 * K);
    const char* XG = (const char*)(XT + ((size_t)b * Nn + n0) * K);
    constexpr int RSTRIDE = K * 2;                // global row stride (bytes)

    f32x16 acc[2][2];
#pragma unroll
    for (int a = 0; a < 2; ++a)
#pragma unroll
        for (int bb = 0; bb < 2; ++bb)
#pragma unroll
            for (int r = 0; r < 16; ++r) acc[a][bb][r] = 0.f;

    for (int k0 = 0; k0 < K; k0 += 64) {
        __syncthreads();
        const int kb = k0 * 2;
#pragma unroll
        for (int p = 0; p < 4; ++p) {
            const int o   = (p * 256 + t) * 16;
            const int row = o >> 7;
            const int src = kb + ((o - (row << 4)) & 127);
            gll16(WG + (size_t)row * RSTRIDE + src, As + o);
            gll16(XG + (size_t)row * RSTRIDE + src, Bs + o);
        }
        asm volatile("s_waitcnt vmcnt(0)" ::: "memory");
        __syncthreads();
#pragma unroll
        for (int kc = 0; kc < 4; ++kc) {
            short8 Af[2], Bf[2];
#pragma unroll
            for (int a = 0; a < 2; ++a) {
                const int row = wm + a * 32 + l31;
                const int off = (kc * 32 + hl * 16 + (row << 4)) & 127;
                Af[a] = *(const short8*)(As + row * 128 + off);
            }
#pragma unroll
            for (int bb = 0; bb < 2; ++bb) {
                const int row = wn + bb * 32 + l31;
                const int off = (kc * 32 + hl * 16 + (row << 4)) & 127;
                Bf[bb] = *(const short8*)(Bs + row * 128 + off);
            }
#pragma unroll
            for (int a = 0; a < 2; ++a)
#pragma unroll
                for (int bb = 0; bb < 2; ++bb)
                    acc[a][bb] = __builtin_amdgcn_mfma_f32_32x32x16_bf16(
                        Af[a], Bf[bb], acc[a][bb], 0, 0, 0);
        }
    }

    // epilogue: D row=(r&3)+8*(r>>2)+4*hl, col=l31
#pragma unroll
    for (int a = 0; a < 2; ++a)
#pragma unroll
        for (int r = 0; r < 16; ++r) {
            const int row = (r & 3) + 8 * (r >> 2) + 4 * hl;
            const int o   = m0 + wm + a * 32 + row;
            const float bv = bias[o];
            const size_t base = ((size_t)b * M + o) * Nn + n0 + wn + l31;
#pragma unroll
            for (int bb = 0; bb < 2; ++bb)
                out[base + bb * 32] = acc[a][bb][r] + bv;
        }
}

// ---------------------------------------------------------------------------
extern "C" void kernel_launch(void* const* d_in, const int* in_sizes, int n_in,
                              void* d_out, int out_size, void* d_ws, size_t ws_size,
                              hipStream_t stream)
{
    const float* x     = (const float*)d_in[0];
    const float* Wk    = (const float*)d_in[1];
    const float* bk    = (const float*)d_in[2];
    const float* gamma = (const float*)d_in[3];
    const float* beta  = (const float*)d_in[4];
    const float* Wv    = (const float*)d_in[5];
    const float* bv    = (const float*)d_in[6];
    const float* Ww    = (const float*)d_in[7];
    const float* bw    = (const float*)d_in[8];

    float* out = (float*)d_out;
    float* f1  = out + F1_OFF;
    float* f2  = out + F2_OFF;
    float* val = out + VAL_OFF;

    // workspace packing (51.1 MB), with aliasing over dead xT:
    //   xT    : [0 .. 16,777,216) ushorts   live steps 2-3
    //   featT : alias xT[0 .. 8,388,608)    live steps 5-6
    //   ctxb  : alias xT[8,388,608 .. )     live steps 6-7
    ushort* xT    = (ushort*)d_ws;                       // [B][Nn][Cin]
    ushort* featT = xT;                                  // [B][Nn][Ck]
    ushort* ctxb  = xT + (size_t)8388608;                // [B][Nn][Cv]
    ushort* valB  = xT + (size_t)16777216;               // [B][Cv][Nn]
    ushort* Wkb   = valB + (size_t)8388608;
    ushort* Wvb   = Wkb + 131072;
    ushort* Wwb   = Wvb + 131072;
    float*  ss    = (float*)(Wwb + 131072);              // 512 floats

    // one-time: allow 160 KB dynamic LDS for the attention kernel
    static bool attn_attr_set = false;
    if (!attn_attr_set) {
        (void)hipFuncSetAttribute((const void*)attn_mfma,
                                  hipFuncAttributeMaxDynamicSharedMemorySize,
                                  ATTN_LDS_BYTES);
        attn_attr_set = true;
    }

    // 1) weights -> bf16
    cast_w<<<192, 256, 0, stream>>>(Wk, Wv, Ww, Wkb, Wvb, Wwb);
    // 2) x -> xT bf16 [B][Nn][Cin]
    transpose_c<<<dim3(Nn / 64, Cin / 64, Bn), 256, 0, stream>>>(x, xT, Cin);
    // 3) fused: qk = Wk*x + bk (fp32) AND value = Wv*x + bv (fp32 + bf16)
    gemm_qv<<<dim3(Nn / 128, Ck / 128, Bn), 256, 0, stream>>>(
        xT, Wkb, Wvb, bk, bv, f1, val, valB);
    // 4) BN stats
    bn_stats<<<Ck, 256, 0, stream>>>(f1, gamma, beta, ss);
    // 5) fused: feat = relu(norm(qk)) -> f1, f2 AND featT bf16 (xT dead)
    bn_relu_t<<<dim3(Nn / 64, Ck / 64, Bn), 256, 0, stream>>>(
        f1, ss, f1, f2, featT);
    // 6) flash attention -> ctx bf16 [B][Nn][Cv]
    attn_mfma<<<dim3(Bn, Nn / 128), 512, ATTN_LDS_BYTES, stream>>>(featT, valB, ctxb);
    // 7) out = Ww*ctx + bw
    gemm_bf<256><<<dim3(Nn / 128, Co / 128, Bn), 256, 0, stream>>>(
        ctxb, Wwb, bw, out, Co);
}